// Round 22
// baseline (869.110 us; speedup 1.0000x reference)
//
#include <hip/hip_runtime.h>
#include <math.h>

#define B_ 30
#define S_ 1024
#define D_ 128
#define ET_ 128
#define H_ 4
#define DK_ 32
#define NH_ 128
#define NPOS (B_*S_)   // 30720

// workspace float offsets (total 27,532,800 floats = 110.1 MB)
#define OFF_TE   0L
#define OFF_Q    3932160L
#define OFF_K    7864320L
#define OFF_CTX  11796480L
#define OFF_XS   0L          // aliases TE (dead after q/k proj)
#define OFF_GIF  3932160L    // aliases Q,K + head of CTX (dead after Wo proj)
#define OFF_GIB  15728640L   // aliases tail of CTX
#define OFF_HF   27525120L
#define OFF_HB   27528960L

typedef __attribute__((ext_vector_type(4))) short short4v;
typedef __attribute__((ext_vector_type(8))) short short8v;
typedef __attribute__((ext_vector_type(4))) float f32x4;

__device__ __forceinline__ short f2bf(float x) {
    unsigned u = __builtin_bit_cast(unsigned, x);
    unsigned r = (u + 0x7FFFu + ((u >> 16) & 1u)) >> 16;
    return (short)r;
}
__device__ __forceinline__ float bf2f(short s) {
    unsigned u = ((unsigned)(unsigned short)s) << 16;
    return __builtin_bit_cast(float, u);
}

__device__ __forceinline__ short8v pack8(const float4 a, const float4 b) {
    short8v v;
    v[0]=f2bf(a.x); v[1]=f2bf(a.y); v[2]=f2bf(a.z); v[3]=f2bf(a.w);
    v[4]=f2bf(b.x); v[5]=f2bf(b.y); v[6]=f2bf(b.z); v[7]=f2bf(b.w);
    return v;
}

// split a float8 (two float4) into bf16 hi + bf16 residual lo
__device__ __forceinline__ void pack_hilo(const float4 a, const float4 b,
                                          short8v& hi, short8v& lo) {
    float v[8] = {a.x,a.y,a.z,a.w,b.x,b.y,b.z,b.w};
#pragma unroll
    for (int e = 0; e < 8; ++e) {
        hi[e] = f2bf(v[e]);
        lo[e] = f2bf(v[e] - bf2f(hi[e]));
    }
}

// fast gate transcendentals: v_rcp_f32 (~1e-7 rel err). Contraction-safe.
__device__ __forceinline__ float fsigmoid(float x) {
    return __builtin_amdgcn_rcpf(1.f + __expf(-x));
}
__device__ __forceinline__ float ftanh(float x) {
    return 1.f - 2.f * __builtin_amdgcn_rcpf(__expf(2.f * x) + 1.f);
}

// LDS-only block sync: orders LDS ops (lgkmcnt(0)) but does NOT drain vmcnt,
// so in-flight global prefetch loads survive across the barrier.
__device__ __forceinline__ void sync_lds() {
    asm volatile("s_waitcnt lgkmcnt(0)" ::: "memory");
    __builtin_amdgcn_sched_barrier(0);
    __builtin_amdgcn_s_barrier();
    __builtin_amdgcn_sched_barrier(0);
}

// ---------------------------------------------------------------- time embed
__global__ __launch_bounds__(256) void time_embed_kernel(
    const float* __restrict__ ts, const float* __restrict__ w_lin,
    const float* __restrict__ b_lin, const float* __restrict__ w_per,
    const float* __restrict__ b_per, float* __restrict__ te)
{
    const long idx = (long)blockIdx.x * 256 + threadIdx.x;  // NPOS*128 total
    const int pos = (int)(idx >> 7);
    const int j = (int)(idx & 127);
    const float tv = ts[pos];
    float v;
    if (j == 0) v = tv * w_lin[0] + b_lin[0];
    else        v = sinf(tv * w_per[j-1] + b_per[j-1]);
    te[idx] = v;
}

// --------------------------------------------------- MFMA split-precision GEMM
// Body shared by single- and dual-dispatch kernels (R12/R17 math, absmax
// 1.2e-4). C[m,n] = sum_k A[m,k]*W[n,k] + bias[n]; A,W bf16 hi+lo split;
// A*W ~= Ahi*Whi + Alo*Whi + Ahi*Wlo. 256 thr = 4 waves; tile 64x128;
// K staged 64/iter. REMAP==0 plain; ==1 write m=b*S+s to row s*B+b (Wo);
// ==2 read A row for m=s*B+b from (S-1-s)*B+b (backward gi).
// FOLD==1 adds bias2[n] for n<256 (folds GRU bhh_{r,z} into gi).
template<int REMAP, int FOLD>
__device__ __forceinline__ void gemm_body(
    const float* __restrict__ A, const float* __restrict__ W,
    const float* __restrict__ bias, const float* __restrict__ bias2,
    float* __restrict__ C, int M, int N, int K)
{
    __shared__ short A_hi[64][72], A_lo[64][72];     // 18.4 KB
    __shared__ short W_hi[128][72], W_lo[128][72];   // 36.9 KB
    const int t = threadIdx.x;
    const int m0 = blockIdx.x * 64;
    const int n0 = blockIdx.y * 128;
    const int w = t >> 6, lane = t & 63;
    const int l15 = lane & 15, lg = lane >> 4;

    f32x4 acc[8];
#pragma unroll
    for (int i = 0; i < 8; ++i) acc[i] = (f32x4){0.f,0.f,0.f,0.f};

    for (int k0 = 0; k0 < K; k0 += 64) {
        {   // stage A tile 64x64
            const int r = t >> 2, c16 = (t & 3) * 16;
            const int m = m0 + r;
            long src;
            if (REMAP == 2) {
                const int s = m / B_, bb = m % B_;
                src = (long)((S_-1-s)*B_ + bb) * K;
            } else {
                src = (long)m * K;
            }
            const float4* ap = (const float4*)(A + src + k0 + c16);
            short8v h0, l0, h1, l1;
            pack_hilo(ap[0], ap[1], h0, l0);
            pack_hilo(ap[2], ap[3], h1, l1);
            *(short8v*)&A_hi[r][c16]     = h0;
            *(short8v*)&A_hi[r][c16 + 8] = h1;
            *(short8v*)&A_lo[r][c16]     = l0;
            *(short8v*)&A_lo[r][c16 + 8] = l1;
        }
        {   // stage W tile 128x64 (q runs 0..3 — R10 NaN fix)
            const int n = t >> 1, c32 = (t & 1) * 32;
            const float4* wp = (const float4*)(W + (long)(n0 + n) * K + k0 + c32);
#pragma unroll
            for (int q = 0; q < 4; ++q) {
                short8v h, l;
                pack_hilo(wp[2*q], wp[2*q + 1], h, l);
                *(short8v*)&W_hi[n][c32 + 8*q] = h;
                *(short8v*)&W_lo[n][c32 + 8*q] = l;
            }
        }
        __syncthreads();
#pragma unroll
        for (int kk = 0; kk < 64; kk += 32) {
            short8v ah = *(const short8v*)&A_hi[16*w + l15][kk + 8*lg];
            short8v al = *(const short8v*)&A_lo[16*w + l15][kk + 8*lg];
#pragma unroll
            for (int nf = 0; nf < 8; ++nf) {
                short8v wh = *(const short8v*)&W_hi[16*nf + l15][kk + 8*lg];
                short8v wl = *(const short8v*)&W_lo[16*nf + l15][kk + 8*lg];
                acc[nf] = __builtin_amdgcn_mfma_f32_16x16x32_bf16(ah, wh, acc[nf], 0,0,0);
                acc[nf] = __builtin_amdgcn_mfma_f32_16x16x32_bf16(al, wh, acc[nf], 0,0,0);
                acc[nf] = __builtin_amdgcn_mfma_f32_16x16x32_bf16(ah, wl, acc[nf], 0,0,0);
            }
        }
        __syncthreads();
    }

#pragma unroll
    for (int nf = 0; nf < 8; ++nf) {
#pragma unroll
        for (int r = 0; r < 4; ++r) {
            const int n = n0 + 16*nf + l15;
            const int m = m0 + 16*w + 4*lg + r;
            float v = acc[nf][r] + bias[n];
            if (FOLD) { if (n < 256) v += bias2[n]; }
            if (REMAP == 1) {
                const int bb = m / S_, s = m % S_;
                C[(long)(s*B_ + bb) * N + n] = v;
            } else {
                C[(long)m * N + n] = v;
            }
        }
    }
}

template<int REMAP, int FOLD>
__global__ __launch_bounds__(256) void gemm_mfma_kernel(
    const float* __restrict__ A, const float* __restrict__ W,
    const float* __restrict__ bias, const float* __restrict__ bias2,
    float* __restrict__ C, int M, int N, int K)
{
    gemm_body<REMAP, FOLD>(A, W, bias, bias2, C, M, N, K);
}

// Dual-dispatch GEMM: blockIdx.z routes to parameter set 0 or 1 so two
// independent GEMMs (q&k projections; fwd&bwd gi) run CONCURRENTLY in one
// launch instead of serialized on the stream (each alone is only ~1.9
// blocks/CU — GPU half-idle twice).
template<int REMAPA, int REMAPB, int FOLD>
__global__ __launch_bounds__(256) void gemm_dual_kernel(
    const float* __restrict__ A,
    const float* __restrict__ W0, const float* __restrict__ bias0,
    const float* __restrict__ bias20, float* __restrict__ C0,
    const float* __restrict__ W1, const float* __restrict__ bias1,
    const float* __restrict__ bias21, float* __restrict__ C1,
    int M, int N, int K)
{
    if (blockIdx.z == 0)
        gemm_body<REMAPA, FOLD>(A, W0, bias0, bias20, C0, M, N, K);
    else
        gemm_body<REMAPB, FOLD>(A, W1, bias1, bias21, C1, M, N, K);
}

// ------------------------------------------------------------ fused attention
// MFMA flash attention, p-minus-one formulation (unchanged from R12/R17).
#define SCALE_LOG2 (0.17677669529663687f * 1.4426950408889634f)

__global__ __launch_bounds__(256) void attn_kernel(
    const float* __restrict__ qbuf, const float* __restrict__ kbuf,
    const float* __restrict__ x, float* __restrict__ ctx)
{
    const int qt = blockIdx.x;   // 0..15
    const int h  = blockIdx.y;   // 0..3
    const int b  = blockIdx.z;   // 0..29
    const int q0 = qt * 64;
    const int t  = threadIdx.x;
    const int w    = t >> 6;
    const int lane = t & 63;
    const int l15  = lane & 15;
    const int lg   = lane >> 4;

    __shared__ short K_lds[64][40];     //  5120 B
    __shared__ short XT_lds[128][68];   // 17408 B, XT[d][key]
    __shared__ short P_lds[4][16][88];  // 11264 B, per-wave P' rows

    short8v qf;
    {
        const float* qp = qbuf + ((long)(b*S_ + q0 + 16*w + l15))*ET_ + h*DK_ + 8*lg;
        float4 a = *(const float4*)qp;
        float4 c = *(const float4*)(qp + 4);
        a.x*=SCALE_LOG2; a.y*=SCALE_LOG2; a.z*=SCALE_LOG2; a.w*=SCALE_LOG2;
        c.x*=SCALE_LOG2; c.y*=SCALE_LOG2; c.z*=SCALE_LOG2; c.w*=SCALE_LOG2;
        qf = pack8(a, c);
    }

    short8v ones;
#pragma unroll
    for (int i = 0; i < 8; ++i) ones[i] = (short)0x3F80;  // bf16 1.0

    f32x4 acc[8];
#pragma unroll
    for (int i = 0; i < 8; ++i) acc[i] = (f32x4){0.f,0.f,0.f,0.f};
    float lsum = 0.f;
    const f32x4 zf = (f32x4){0.f,0.f,0.f,0.f};

    for (int kt = 0; kt < 16; ++kt) {
        const int key0 = kt * 64;
        {
            const int key = t >> 2, c8 = (t & 3) * 8;
            const float* kp = kbuf + ((long)(b*S_ + key0 + key))*ET_ + h*DK_ + c8;
            float4 a = *(const float4*)kp;
            float4 c = *(const float4*)(kp + 4);
            *(short8v*)&K_lds[key][c8] = pack8(a, c);
        }
        {
            const int k2 = t & 31;
            const int dg = t >> 5;
            const float* xp0 = x + ((long)(b*S_ + key0 + 2*k2))*D_ + 16*dg;
            const float* xp1 = xp0 + D_;
            float v0[16], v1[16];
#pragma unroll
            for (int j4 = 0; j4 < 4; ++j4) {
                float4 a = ((const float4*)xp0)[j4];
                float4 c = ((const float4*)xp1)[j4];
                v0[4*j4+0]=a.x; v0[4*j4+1]=a.y; v0[4*j4+2]=a.z; v0[4*j4+3]=a.w;
                v1[4*j4+0]=c.x; v1[4*j4+1]=c.y; v1[4*j4+2]=c.z; v1[4*j4+3]=c.w;
            }
#pragma unroll
            for (int j = 0; j < 16; ++j) {
                unsigned u = (unsigned)(unsigned short)f2bf(v0[j])
                           | ((unsigned)(unsigned short)f2bf(v1[j]) << 16);
                *(unsigned*)&XT_lds[16*dg + j][2*k2] = u;
            }
        }
        __syncthreads();

        f32x4 sc[4];
#pragma unroll
        for (int f = 0; f < 4; ++f) {
            short8v kf = *(const short8v*)&K_lds[16*f + l15][8*lg];
            sc[f] = __builtin_amdgcn_mfma_f32_16x16x32_bf16(kf, qf, zf, 0, 0, 0);
        }

        float pw[4][4];
        float ps = 0.f;
#pragma unroll
        for (int f = 0; f < 4; ++f)
#pragma unroll
            for (int r = 0; r < 4; ++r) {
                const float p = exp2f(sc[f][r]);
                ps += p;
                pw[f][r] = p - 1.f;
            }
        ps += __shfl_xor(ps, 16);
        ps += __shfl_xor(ps, 32);
        lsum += ps;

#pragma unroll
        for (int f = 0; f < 4; ++f) {
            unsigned lo = (unsigned)(unsigned short)f2bf(pw[f][0])
                        | ((unsigned)(unsigned short)f2bf(pw[f][1]) << 16);
            unsigned hi = (unsigned)(unsigned short)f2bf(pw[f][2])
                        | ((unsigned)(unsigned short)f2bf(pw[f][3]) << 16);
            *(unsigned*)&P_lds[w][l15][16*f + 4*lg]     = lo;
            *(unsigned*)&P_lds[w][l15][16*f + 4*lg + 2] = hi;
        }

#pragma unroll
        for (int kb = 0; kb < 2; ++kb) {
            short8v pa = *(const short8v*)&P_lds[w][l15][32*kb + 8*lg];
#pragma unroll
            for (int dq = 0; dq < 8; ++dq) {
                const short* xr = &XT_lds[16*dq + l15][32*kb + 8*lg];
                short4v lo = *(const short4v*)xr;
                short4v hi = *(const short4v*)(xr + 4);
                short8v xb = __builtin_shufflevector(lo, hi, 0,1,2,3,4,5,6,7);
                acc[dq] = __builtin_amdgcn_mfma_f32_16x16x32_bf16(ones, xb, acc[dq], 0, 0, 0);
                acc[dq] = __builtin_amdgcn_mfma_f32_16x16x32_bf16(pa,   xb, acc[dq], 0, 0, 0);
            }
        }
        __syncthreads();
    }

    const float inv = 1.f / lsum;
#pragma unroll
    for (int r = 0; r < 4; ++r) {
        const float ir = __shfl(inv, (lane & 48) | (4*lg + r));
        const long base = ((long)(b*S_ + q0 + 16*w + 4*lg + r)*H_ + h)*D_ + l15;
#pragma unroll
        for (int d = 0; d < 8; ++d)
            ctx[base + (long)d*16] = acc[d][r] * ir;
    }
}

// ----------------------------------------------------------------- GRU scan
// R21 config (best measured: 548us GRU): 2 waves x 128 thr; swapped MFMA
// operands (h broadcast as A, weights as B: col=l15, k=8lg+e) so
// D[r][l15] = gh[tile_base + l15] for all r/lg; lane owns
// j = 64wv + 16lg + l15 -> 4-way A-select keyed on lg (9 cndmasks).
// 48 MFMAs/wave/step, 1 trans-set/lane, ONE sync_lds/step, plain-bf16 h.
// VGPR ~220, no spill. Gate replication across waves BANNED (R9/16/18);
// cross-lane on serial path BANNED (R14).
__global__ __launch_bounds__(128, 1) void gru_kernel(
    const float* __restrict__ gi_f, const float* __restrict__ gi_b,
    const float* __restrict__ Whh_f, const float* __restrict__ bhh_f,
    const float* __restrict__ Whh_b, const float* __restrict__ bhh_b,
    float* __restrict__ hf, float* __restrict__ hb)
{
    const int bid = blockIdx.x;
    const int dir = bid / B_;
    const int b   = bid % B_;
    const float* gi  = dir ? gi_b  : gi_f;
    const float* Whh = dir ? Whh_b : Whh_f;
    const float* bhh = dir ? bhh_b : bhh_f;
    float* hout      = dir ? hb    : hf;
    const int t    = threadIdx.x;        // 0..127
    const int wv   = t >> 6;             // wave 0/1 -> h half
    const int lane = t & 63;
    const int l15  = lane & 15;
    const int lg   = lane >> 4;
    const int j    = 64*wv + 16*lg + l15;   // owned h index (A = lg)

    short8v wa[3][4][4];
#pragma unroll
    for (int g = 0; g < 3; ++g)
#pragma unroll
        for (int A = 0; A < 4; ++A) {
            const int row = 128*g + 64*wv + 16*A + l15;
#pragma unroll
            for (int kf = 0; kf < 4; ++kf) {
                const float* wp = Whh + (long)row*128 + 32*kf + 8*lg;
                float4 a = *(const float4*)wp;
                float4 c = *(const float4*)(wp + 4);
                wa[g][A][kf] = pack8(a, c);
            }
        }

    const float bnj = bhh[256 + j];      // r,z biases folded into gi by GEMM

    __shared__ __align__(16) short hbf[2][128];   // bf16 h, double-buffered
    hbf[0][t] = 0;

    float hcur = 0.f;

    float gar=0.f, gaz=0.f, gan=0.f, gbr=0.f, gbz=0.f, gbn=0.f;
    float gcr=0.f, gcz=0.f, gcn=0.f, gdr=0.f, gdz=0.f, gdn=0.f;
    {
        const float* g0 = gi + (long)b * 384;
        gar = g0[j]; gaz = g0[128+j]; gan = g0[256+j];
        const float* g1 = gi + ((long)B_ + b) * 384;
        gbr = g1[j]; gbz = g1[128+j]; gbn = g1[256+j];
    }
    __syncthreads();   // one-time full sync

#define LOADGI(R, Z, N, SS)                                                    \
    if ((SS) < S_) {                                                           \
        const float* g = gi + ((long)(SS)*B_ + b) * 384;                       \
        R = g[j]; Z = g[128+j]; N = g[256+j];                                  \
    }

#define GRU_STEP(CUR, GR, GZ, GN)                                              \
    {                                                                          \
        short8v hfrag[4];                                                      \
        _Pragma("unroll")                                                      \
        for (int kf = 0; kf < 4; ++kf)                                         \
            hfrag[kf] = *(const short8v*)&hbf[CUR][32*kf + 8*lg];              \
        f32x4 acc[3][4];                                                       \
        _Pragma("unroll")                                                      \
        for (int g = 0; g < 3; ++g)                                            \
            _Pragma("unroll")                                                  \
            for (int A = 0; A < 4; ++A)                                        \
                acc[g][A] = (f32x4){0.f,0.f,0.f,0.f};                          \
        _Pragma("unroll")                                                      \
        for (int kf = 0; kf < 4; ++kf)                                         \
            _Pragma("unroll")                                                  \
            for (int g = 0; g < 3; ++g)                                        \
                _Pragma("unroll")                                              \
                for (int A = 0; A < 4; ++A)                                    \
                    acc[g][A] = __builtin_amdgcn_mfma_f32_16x16x32_bf16(       \
                        hfrag[kf], wa[g][A][kf], acc[g][A], 0,0,0);            \
        float ghr = acc[0][0][0];                                              \
        float ghz = acc[1][0][0];                                              \
        float ghn = acc[2][0][0];                                              \
        _Pragma("unroll")                                                      \
        for (int A = 1; A < 4; ++A) {                                          \
            const bool c = (lg == A);                                          \
            ghr = c ? acc[0][A][0] : ghr;                                      \
            ghz = c ? acc[1][A][0] : ghz;                                      \
            ghn = c ? acc[2][A][0] : ghn;                                      \
        }                                                                      \
        const float r = fsigmoid(GR + ghr);                                    \
        const float z = fsigmoid(GZ + ghz);                                    \
        const float n = ftanh (GN + r * (ghn + bnj));                          \
        hcur = (1.f - z)*n + z*hcur;                                           \
        hbf[(CUR)^1][j] = f2bf(hcur);                                          \
        sync_lds();                                                            \
    }

    for (int s = 0; s < S_; s += 4) {
        LOADGI(gcr, gcz, gcn, s + 2)     // 2 steps of slack before use
        GRU_STEP(0, gar, gaz, gan)
        LOADGI(gdr, gdz, gdn, s + 3)
        GRU_STEP(1, gbr, gbz, gbn)
        LOADGI(gar, gaz, gan, s + 4)
        GRU_STEP(0, gcr, gcz, gcn)
        LOADGI(gbr, gbz, gbn, s + 5)
        GRU_STEP(1, gdr, gdz, gdn)
    }
#undef GRU_STEP
#undef LOADGI

    hout[(long)b*128 + j] = hcur;
}

// -------------------------------------------------------------- classifier
__global__ __launch_bounds__(128) void classifier_kernel(
    const float* __restrict__ hf, const float* __restrict__ hb,
    const float* __restrict__ W1, const float* __restrict__ b1,
    const float* __restrict__ W2, const float* __restrict__ b2,
    const float* __restrict__ W3, const float* __restrict__ b3,
    float* __restrict__ out)
{
    const int b = blockIdx.x;
    const int t = threadIdx.x;
    __shared__ float cin[256], a1[128], a2[64];
    cin[t]       = hf[(long)b*128 + t];
    cin[128 + t] = hb[(long)b*128 + t];
    __syncthreads();
    {
        float a = b1[t];
        for (int i = 0; i < 256; ++i) a = fmaf(W1[(long)t*256 + i], cin[i], a);
        a1[t] = a;
    }
    __syncthreads();
    if (t < 64) {
        float a = b2[t];
        for (int i = 0; i < 128; ++i) a = fmaf(W2[(long)t*128 + i], a1[i], a);
        a2[t] = a;
    }
    __syncthreads();
    if (t < 6) {
        float a = b3[t];
        for (int i = 0; i < 64; ++i) a = fmaf(W3[(long)t*64 + i], a2[i], a);
        out[(long)b*6 + t] = a;
    }
}

// ------------------------------------------------------------------- launch
extern "C" void kernel_launch(void* const* d_in, const int* in_sizes, int n_in,
                              void* d_out, int out_size, void* d_ws, size_t ws_size,
                              hipStream_t stream)
{
    const float* x     = (const float*)d_in[0];
    const float* ts    = (const float*)d_in[1];
    const float* w_lin = (const float*)d_in[2];
    const float* b_lin = (const float*)d_in[3];
    const float* w_per = (const float*)d_in[4];
    const float* b_per = (const float*)d_in[5];
    const float* Wq    = (const float*)d_in[6];
    const float* bq    = (const float*)d_in[7];
    const float* Wk    = (const float*)d_in[8];
    const float* bk    = (const float*)d_in[9];
    const float* Wo    = (const float*)d_in[10];
    const float* bo    = (const float*)d_in[11];
    const float* Wih_f = (const float*)d_in[12];
    const float* Whh_f = (const float*)d_in[13];
    const float* bih_f = (const float*)d_in[14];
    const float* bhh_f = (const float*)d_in[15];
    const float* Wih_b = (const float*)d_in[16];
    const float* Whh_b = (const float*)d_in[17];
    const float* bih_b = (const float*)d_in[18];
    const float* bhh_b = (const float*)d_in[19];
    const float* W1    = (const float*)d_in[20];
    const float* b1    = (const float*)d_in[21];
    const float* W2    = (const float*)d_in[22];
    const float* b2    = (const float*)d_in[23];
    const float* W3    = (const float*)d_in[24];
    const float* b3    = (const float*)d_in[25];
    float* out = (float*)d_out;
    float* ws  = (float*)d_ws;

    float* te  = ws + OFF_TE;
    float* q   = ws + OFF_Q;
    float* k   = ws + OFF_K;
    float* ctx = ws + OFF_CTX;
    float* xs  = ws + OFF_XS;
    float* gif = ws + OFF_GIF;
    float* gib = ws + OFF_GIB;
    float* hf  = ws + OFF_HF;
    float* hb  = ws + OFF_HB;

    time_embed_kernel<<<NPOS*128/256, 256, 0, stream>>>(ts, w_lin, b_lin, w_per, b_per, te);
    // q and k projections fused into one launch (z selects param set)
    gemm_dual_kernel<0,0,0><<<dim3(NPOS/64, 1, 2), 256, 0, stream>>>(
        te, Wq, bq, nullptr, q, Wk, bk, nullptr, k, NPOS, 128, 128);
    attn_kernel<<<dim3(16, 4, 30), 256, 0, stream>>>(q, k, x, ctx);
    gemm_mfma_kernel<1,0><<<dim3(NPOS/64, 1), 256, 0, stream>>>(ctx, Wo, bo, nullptr, xs, NPOS, 128, 512);
    // forward and backward gi GEMMs fused into one launch
    gemm_dual_kernel<0,2,1><<<dim3(NPOS/64, 3, 2), 256, 0, stream>>>(
        xs, Wih_f, bih_f, bhh_f, gif, Wih_b, bih_b, bhh_b, gib, NPOS, 384, 128);
    gru_kernel<<<60, 128, 0, stream>>>(gif, gib, Whh_f, bhh_f, Whh_b, bhh_b, hf, hb);
    classifier_kernel<<<30, 128, 0, stream>>>(hf, hb, W1, b1, W2, b2, W3, b3, out);
}

// Round 23
// 826.819 us; speedup vs baseline: 1.0511x; 1.0511x over previous
//
#include <hip/hip_runtime.h>
#include <math.h>

#define B_ 30
#define S_ 1024
#define D_ 128
#define ET_ 128
#define H_ 4
#define DK_ 32
#define NH_ 128
#define NPOS (B_*S_)   // 30720

// workspace float offsets (total 27,532,800 floats = 110.1 MB)
#define OFF_TE   0L
#define OFF_Q    3932160L
#define OFF_K    7864320L
#define OFF_CTX  11796480L
#define OFF_XS   0L          // aliases TE (dead after q/k proj)
#define OFF_GIF  3932160L    // aliases Q,K + head of CTX (dead after Wo proj)
#define OFF_GIB  15728640L   // aliases tail of CTX
#define OFF_HF   27525120L
#define OFF_HB   27528960L

typedef __attribute__((ext_vector_type(4))) short short4v;
typedef __attribute__((ext_vector_type(8))) short short8v;
typedef __attribute__((ext_vector_type(4))) float f32x4;

__device__ __forceinline__ short f2bf(float x) {
    unsigned u = __builtin_bit_cast(unsigned, x);
    unsigned r = (u + 0x7FFFu + ((u >> 16) & 1u)) >> 16;
    return (short)r;
}
__device__ __forceinline__ float bf2f(short s) {
    unsigned u = ((unsigned)(unsigned short)s) << 16;
    return __builtin_bit_cast(float, u);
}

__device__ __forceinline__ short8v pack8(const float4 a, const float4 b) {
    short8v v;
    v[0]=f2bf(a.x); v[1]=f2bf(a.y); v[2]=f2bf(a.z); v[3]=f2bf(a.w);
    v[4]=f2bf(b.x); v[5]=f2bf(b.y); v[6]=f2bf(b.z); v[7]=f2bf(b.w);
    return v;
}

// split a float8 (two float4) into bf16 hi + bf16 residual lo
__device__ __forceinline__ void pack_hilo(const float4 a, const float4 b,
                                          short8v& hi, short8v& lo) {
    float v[8] = {a.x,a.y,a.z,a.w,b.x,b.y,b.z,b.w};
#pragma unroll
    for (int e = 0; e < 8; ++e) {
        hi[e] = f2bf(v[e]);
        lo[e] = f2bf(v[e] - bf2f(hi[e]));
    }
}

// fast gate transcendentals: v_rcp_f32 (~1e-7 rel err). Contraction-safe.
__device__ __forceinline__ float fsigmoid(float x) {
    return __builtin_amdgcn_rcpf(1.f + __expf(-x));
}
__device__ __forceinline__ float ftanh(float x) {
    return 1.f - 2.f * __builtin_amdgcn_rcpf(__expf(2.f * x) + 1.f);
}

// LDS-only block sync: orders LDS ops (lgkmcnt(0)) but does NOT drain vmcnt,
// so in-flight global prefetch loads survive across the barrier.
__device__ __forceinline__ void sync_lds() {
    asm volatile("s_waitcnt lgkmcnt(0)" ::: "memory");
    __builtin_amdgcn_sched_barrier(0);
    __builtin_amdgcn_s_barrier();
    __builtin_amdgcn_sched_barrier(0);
}

// ---------------------------------------------------------------- time embed
__global__ __launch_bounds__(256) void time_embed_kernel(
    const float* __restrict__ ts, const float* __restrict__ w_lin,
    const float* __restrict__ b_lin, const float* __restrict__ w_per,
    const float* __restrict__ b_per, float* __restrict__ te)
{
    const long idx = (long)blockIdx.x * 256 + threadIdx.x;  // NPOS*128 total
    const int pos = (int)(idx >> 7);
    const int j = (int)(idx & 127);
    const float tv = ts[pos];
    float v;
    if (j == 0) v = tv * w_lin[0] + b_lin[0];
    else        v = sinf(tv * w_per[j-1] + b_per[j-1]);
    te[idx] = v;
}

// --------------------------------------------------- MFMA split-precision GEMM
// Body shared by single- and dual-dispatch kernels (R12/R17 math, absmax
// 1.2e-4). SHARED TILES ARE PASSED IN BY REFERENCE (R22 post-mortem: when
// declared inside the inlined body, the dual kernel's two branches got two
// disjoint ~55KB LDS allocations -> occupancy 2->1 blocks/CU, regression).
template<int REMAP, int FOLD>
__device__ __forceinline__ void gemm_body(
    const float* __restrict__ A, const float* __restrict__ W,
    const float* __restrict__ bias, const float* __restrict__ bias2,
    float* __restrict__ C, int M, int N, int K,
    short (&A_hi)[64][72], short (&A_lo)[64][72],
    short (&W_hi)[128][72], short (&W_lo)[128][72])
{
    const int t = threadIdx.x;
    const int m0 = blockIdx.x * 64;
    const int n0 = blockIdx.y * 128;
    const int w = t >> 6, lane = t & 63;
    const int l15 = lane & 15, lg = lane >> 4;

    f32x4 acc[8];
#pragma unroll
    for (int i = 0; i < 8; ++i) acc[i] = (f32x4){0.f,0.f,0.f,0.f};

    for (int k0 = 0; k0 < K; k0 += 64) {
        {   // stage A tile 64x64
            const int r = t >> 2, c16 = (t & 3) * 16;
            const int m = m0 + r;
            long src;
            if (REMAP == 2) {
                const int s = m / B_, bb = m % B_;
                src = (long)((S_-1-s)*B_ + bb) * K;
            } else {
                src = (long)m * K;
            }
            const float4* ap = (const float4*)(A + src + k0 + c16);
            short8v h0, l0, h1, l1;
            pack_hilo(ap[0], ap[1], h0, l0);
            pack_hilo(ap[2], ap[3], h1, l1);
            *(short8v*)&A_hi[r][c16]     = h0;
            *(short8v*)&A_hi[r][c16 + 8] = h1;
            *(short8v*)&A_lo[r][c16]     = l0;
            *(short8v*)&A_lo[r][c16 + 8] = l1;
        }
        {   // stage W tile 128x64 (q runs 0..3 — R10 NaN fix)
            const int n = t >> 1, c32 = (t & 1) * 32;
            const float4* wp = (const float4*)(W + (long)(n0 + n) * K + k0 + c32);
#pragma unroll
            for (int q = 0; q < 4; ++q) {
                short8v h, l;
                pack_hilo(wp[2*q], wp[2*q + 1], h, l);
                *(short8v*)&W_hi[n][c32 + 8*q] = h;
                *(short8v*)&W_lo[n][c32 + 8*q] = l;
            }
        }
        __syncthreads();
#pragma unroll
        for (int kk = 0; kk < 64; kk += 32) {
            short8v ah = *(const short8v*)&A_hi[16*w + l15][kk + 8*lg];
            short8v al = *(const short8v*)&A_lo[16*w + l15][kk + 8*lg];
#pragma unroll
            for (int nf = 0; nf < 8; ++nf) {
                short8v wh = *(const short8v*)&W_hi[16*nf + l15][kk + 8*lg];
                short8v wl = *(const short8v*)&W_lo[16*nf + l15][kk + 8*lg];
                acc[nf] = __builtin_amdgcn_mfma_f32_16x16x32_bf16(ah, wh, acc[nf], 0,0,0);
                acc[nf] = __builtin_amdgcn_mfma_f32_16x16x32_bf16(al, wh, acc[nf], 0,0,0);
                acc[nf] = __builtin_amdgcn_mfma_f32_16x16x32_bf16(ah, wl, acc[nf], 0,0,0);
            }
        }
        __syncthreads();
    }

#pragma unroll
    for (int nf = 0; nf < 8; ++nf) {
#pragma unroll
        for (int r = 0; r < 4; ++r) {
            const int n = n0 + 16*nf + l15;
            const int m = m0 + 16*w + 4*lg + r;
            float v = acc[nf][r] + bias[n];
            if (FOLD) { if (n < 256) v += bias2[n]; }
            if (REMAP == 1) {
                const int bb = m / S_, s = m % S_;
                C[(long)(s*B_ + bb) * N + n] = v;
            } else {
                C[(long)m * N + n] = v;
            }
        }
    }
}

template<int REMAP, int FOLD>
__global__ __launch_bounds__(256) void gemm_mfma_kernel(
    const float* __restrict__ A, const float* __restrict__ W,
    const float* __restrict__ bias, const float* __restrict__ bias2,
    float* __restrict__ C, int M, int N, int K)
{
    __shared__ short A_hi[64][72], A_lo[64][72];     // 18.4 KB
    __shared__ short W_hi[128][72], W_lo[128][72];   // 36.9 KB
    gemm_body<REMAP, FOLD>(A, W, bias, bias2, C, M, N, K,
                           A_hi, A_lo, W_hi, W_lo);
}

// Dual-dispatch GEMM: blockIdx.z routes to parameter set 0 or 1 so two
// independent GEMMs (q&k projections; fwd&bwd gi) run CONCURRENTLY in one
// launch. Shared tiles declared HERE (once) and passed to both branches.
template<int REMAPA, int REMAPB, int FOLD>
__global__ __launch_bounds__(256) void gemm_dual_kernel(
    const float* __restrict__ A,
    const float* __restrict__ W0, const float* __restrict__ bias0,
    const float* __restrict__ bias20, float* __restrict__ C0,
    const float* __restrict__ W1, const float* __restrict__ bias1,
    const float* __restrict__ bias21, float* __restrict__ C1,
    int M, int N, int K)
{
    __shared__ short A_hi[64][72], A_lo[64][72];     // 18.4 KB (shared by both)
    __shared__ short W_hi[128][72], W_lo[128][72];   // 36.9 KB
    if (blockIdx.z == 0)
        gemm_body<REMAPA, FOLD>(A, W0, bias0, bias20, C0, M, N, K,
                                A_hi, A_lo, W_hi, W_lo);
    else
        gemm_body<REMAPB, FOLD>(A, W1, bias1, bias21, C1, M, N, K,
                                A_hi, A_lo, W_hi, W_lo);
}

// ------------------------------------------------------------ fused attention
// MFMA flash attention, p-minus-one formulation (unchanged from R12/R17).
#define SCALE_LOG2 (0.17677669529663687f * 1.4426950408889634f)

__global__ __launch_bounds__(256) void attn_kernel(
    const float* __restrict__ qbuf, const float* __restrict__ kbuf,
    const float* __restrict__ x, float* __restrict__ ctx)
{
    const int qt = blockIdx.x;   // 0..15
    const int h  = blockIdx.y;   // 0..3
    const int b  = blockIdx.z;   // 0..29
    const int q0 = qt * 64;
    const int t  = threadIdx.x;
    const int w    = t >> 6;
    const int lane = t & 63;
    const int l15  = lane & 15;
    const int lg   = lane >> 4;

    __shared__ short K_lds[64][40];     //  5120 B
    __shared__ short XT_lds[128][68];   // 17408 B, XT[d][key]
    __shared__ short P_lds[4][16][88];  // 11264 B, per-wave P' rows

    short8v qf;
    {
        const float* qp = qbuf + ((long)(b*S_ + q0 + 16*w + l15))*ET_ + h*DK_ + 8*lg;
        float4 a = *(const float4*)qp;
        float4 c = *(const float4*)(qp + 4);
        a.x*=SCALE_LOG2; a.y*=SCALE_LOG2; a.z*=SCALE_LOG2; a.w*=SCALE_LOG2;
        c.x*=SCALE_LOG2; c.y*=SCALE_LOG2; c.z*=SCALE_LOG2; c.w*=SCALE_LOG2;
        qf = pack8(a, c);
    }

    short8v ones;
#pragma unroll
    for (int i = 0; i < 8; ++i) ones[i] = (short)0x3F80;  // bf16 1.0

    f32x4 acc[8];
#pragma unroll
    for (int i = 0; i < 8; ++i) acc[i] = (f32x4){0.f,0.f,0.f,0.f};
    float lsum = 0.f;
    const f32x4 zf = (f32x4){0.f,0.f,0.f,0.f};

    for (int kt = 0; kt < 16; ++kt) {
        const int key0 = kt * 64;
        {
            const int key = t >> 2, c8 = (t & 3) * 8;
            const float* kp = kbuf + ((long)(b*S_ + key0 + key))*ET_ + h*DK_ + c8;
            float4 a = *(const float4*)kp;
            float4 c = *(const float4*)(kp + 4);
            *(short8v*)&K_lds[key][c8] = pack8(a, c);
        }
        {
            const int k2 = t & 31;
            const int dg = t >> 5;
            const float* xp0 = x + ((long)(b*S_ + key0 + 2*k2))*D_ + 16*dg;
            const float* xp1 = xp0 + D_;
            float v0[16], v1[16];
#pragma unroll
            for (int j4 = 0; j4 < 4; ++j4) {
                float4 a = ((const float4*)xp0)[j4];
                float4 c = ((const float4*)xp1)[j4];
                v0[4*j4+0]=a.x; v0[4*j4+1]=a.y; v0[4*j4+2]=a.z; v0[4*j4+3]=a.w;
                v1[4*j4+0]=c.x; v1[4*j4+1]=c.y; v1[4*j4+2]=c.z; v1[4*j4+3]=c.w;
            }
#pragma unroll
            for (int j = 0; j < 16; ++j) {
                unsigned u = (unsigned)(unsigned short)f2bf(v0[j])
                           | ((unsigned)(unsigned short)f2bf(v1[j]) << 16);
                *(unsigned*)&XT_lds[16*dg + j][2*k2] = u;
            }
        }
        __syncthreads();

        f32x4 sc[4];
#pragma unroll
        for (int f = 0; f < 4; ++f) {
            short8v kf = *(const short8v*)&K_lds[16*f + l15][8*lg];
            sc[f] = __builtin_amdgcn_mfma_f32_16x16x32_bf16(kf, qf, zf, 0, 0, 0);
        }

        float pw[4][4];
        float ps = 0.f;
#pragma unroll
        for (int f = 0; f < 4; ++f)
#pragma unroll
            for (int r = 0; r < 4; ++r) {
                const float p = exp2f(sc[f][r]);
                ps += p;
                pw[f][r] = p - 1.f;
            }
        ps += __shfl_xor(ps, 16);
        ps += __shfl_xor(ps, 32);
        lsum += ps;

#pragma unroll
        for (int f = 0; f < 4; ++f) {
            unsigned lo = (unsigned)(unsigned short)f2bf(pw[f][0])
                        | ((unsigned)(unsigned short)f2bf(pw[f][1]) << 16);
            unsigned hi = (unsigned)(unsigned short)f2bf(pw[f][2])
                        | ((unsigned)(unsigned short)f2bf(pw[f][3]) << 16);
            *(unsigned*)&P_lds[w][l15][16*f + 4*lg]     = lo;
            *(unsigned*)&P_lds[w][l15][16*f + 4*lg + 2] = hi;
        }

#pragma unroll
        for (int kb = 0; kb < 2; ++kb) {
            short8v pa = *(const short8v*)&P_lds[w][l15][32*kb + 8*lg];
#pragma unroll
            for (int dq = 0; dq < 8; ++dq) {
                const short* xr = &XT_lds[16*dq + l15][32*kb + 8*lg];
                short4v lo = *(const short4v*)xr;
                short4v hi = *(const short4v*)(xr + 4);
                short8v xb = __builtin_shufflevector(lo, hi, 0,1,2,3,4,5,6,7);
                acc[dq] = __builtin_amdgcn_mfma_f32_16x16x32_bf16(ones, xb, acc[dq], 0, 0, 0);
                acc[dq] = __builtin_amdgcn_mfma_f32_16x16x32_bf16(pa,   xb, acc[dq], 0, 0, 0);
            }
        }
        __syncthreads();
    }

    const float inv = 1.f / lsum;
#pragma unroll
    for (int r = 0; r < 4; ++r) {
        const float ir = __shfl(inv, (lane & 48) | (4*lg + r));
        const long base = ((long)(b*S_ + q0 + 16*w + 4*lg + r)*H_ + h)*D_ + l15;
#pragma unroll
        for (int d = 0; d < 8; ++d)
            ctx[base + (long)d*16] = acc[d][r] * ir;
    }
}

// ----------------------------------------------------------------- GRU scan
// R21 config (best measured: 548us GRU): 2 waves x 128 thr; swapped MFMA
// operands (h broadcast as A, weights as B: col=l15, k=8lg+e) so
// D[r][l15] = gh[tile_base + l15] for all r/lg; lane owns
// j = 64wv + 16lg + l15 -> 4-way A-select keyed on lg (9 cndmasks).
// 48 MFMAs/wave/step, 1 trans-set/lane, ONE sync_lds/step, plain-bf16 h.
// VGPR ~220, no spill.
__global__ __launch_bounds__(128, 1) void gru_kernel(
    const float* __restrict__ gi_f, const float* __restrict__ gi_b,
    const float* __restrict__ Whh_f, const float* __restrict__ bhh_f,
    const float* __restrict__ Whh_b, const float* __restrict__ bhh_b,
    float* __restrict__ hf, float* __restrict__ hb)
{
    const int bid = blockIdx.x;
    const int dir = bid / B_;
    const int b   = bid % B_;
    const float* gi  = dir ? gi_b  : gi_f;
    const float* Whh = dir ? Whh_b : Whh_f;
    const float* bhh = dir ? bhh_b : bhh_f;
    float* hout      = dir ? hb    : hf;
    const int t    = threadIdx.x;        // 0..127
    const int wv   = t >> 6;             // wave 0/1 -> h half
    const int lane = t & 63;
    const int l15  = lane & 15;
    const int lg   = lane >> 4;
    const int j    = 64*wv + 16*lg + l15;   // owned h index (A = lg)

    short8v wa[3][4][4];
#pragma unroll
    for (int g = 0; g < 3; ++g)
#pragma unroll
        for (int A = 0; A < 4; ++A) {
            const int row = 128*g + 64*wv + 16*A + l15;
#pragma unroll
            for (int kf = 0; kf < 4; ++kf) {
                const float* wp = Whh + (long)row*128 + 32*kf + 8*lg;
                float4 a = *(const float4*)wp;
                float4 c = *(const float4*)(wp + 4);
                wa[g][A][kf] = pack8(a, c);
            }
        }

    const float bnj = bhh[256 + j];      // r,z biases folded into gi by GEMM

    __shared__ __align__(16) short hbf[2][128];   // bf16 h, double-buffered
    hbf[0][t] = 0;

    float hcur = 0.f;

    float gar=0.f, gaz=0.f, gan=0.f, gbr=0.f, gbz=0.f, gbn=0.f;
    float gcr=0.f, gcz=0.f, gcn=0.f, gdr=0.f, gdz=0.f, gdn=0.f;
    {
        const float* g0 = gi + (long)b * 384;
        gar = g0[j]; gaz = g0[128+j]; gan = g0[256+j];
        const float* g1 = gi + ((long)B_ + b) * 384;
        gbr = g1[j]; gbz = g1[128+j]; gbn = g1[256+j];
    }
    __syncthreads();   // one-time full sync

#define LOADGI(R, Z, N, SS)                                                    \
    if ((SS) < S_) {                                                           \
        const float* g = gi + ((long)(SS)*B_ + b) * 384;                       \
        R = g[j]; Z = g[128+j]; N = g[256+j];                                  \
    }

#define GRU_STEP(CUR, GR, GZ, GN)                                              \
    {                                                                          \
        short8v hfrag[4];                                                      \
        _Pragma("unroll")                                                      \
        for (int kf = 0; kf < 4; ++kf)                                         \
            hfrag[kf] = *(const short8v*)&hbf[CUR][32*kf + 8*lg];              \
        f32x4 acc[3][4];                                                       \
        _Pragma("unroll")                                                      \
        for (int g = 0; g < 3; ++g)                                            \
            _Pragma("unroll")                                                  \
            for (int A = 0; A < 4; ++A)                                        \
                acc[g][A] = (f32x4){0.f,0.f,0.f,0.f};                          \
        _Pragma("unroll")                                                      \
        for (int kf = 0; kf < 4; ++kf)                                         \
            _Pragma("unroll")                                                  \
            for (int g = 0; g < 3; ++g)                                        \
                _Pragma("unroll")                                              \
                for (int A = 0; A < 4; ++A)                                    \
                    acc[g][A] = __builtin_amdgcn_mfma_f32_16x16x32_bf16(       \
                        hfrag[kf], wa[g][A][kf], acc[g][A], 0,0,0);            \
        float ghr = acc[0][0][0];                                              \
        float ghz = acc[1][0][0];                                              \
        float ghn = acc[2][0][0];                                              \
        _Pragma("unroll")                                                      \
        for (int A = 1; A < 4; ++A) {                                          \
            const bool c = (lg == A);                                          \
            ghr = c ? acc[0][A][0] : ghr;                                      \
            ghz = c ? acc[1][A][0] : ghz;                                      \
            ghn = c ? acc[2][A][0] : ghn;                                      \
        }                                                                      \
        const float r = fsigmoid(GR + ghr);                                    \
        const float z = fsigmoid(GZ + ghz);                                    \
        const float n = ftanh (GN + r * (ghn + bnj));                          \
        hcur = (1.f - z)*n + z*hcur;                                           \
        hbf[(CUR)^1][j] = f2bf(hcur);                                          \
        sync_lds();                                                            \
    }

    for (int s = 0; s < S_; s += 4) {
        LOADGI(gcr, gcz, gcn, s + 2)     // 2 steps of slack before use
        GRU_STEP(0, gar, gaz, gan)
        LOADGI(gdr, gdz, gdn, s + 3)
        GRU_STEP(1, gbr, gbz, gbn)
        LOADGI(gar, gaz, gan, s + 4)
        GRU_STEP(0, gcr, gcz, gcn)
        LOADGI(gbr, gbz, gbn, s + 5)
        GRU_STEP(1, gdr, gdz, gdn)
    }
#undef GRU_STEP
#undef LOADGI

    hout[(long)b*128 + j] = hcur;
}

// -------------------------------------------------------------- classifier
__global__ __launch_bounds__(128) void classifier_kernel(
    const float* __restrict__ hf, const float* __restrict__ hb,
    const float* __restrict__ W1, const float* __restrict__ b1,
    const float* __restrict__ W2, const float* __restrict__ b2,
    const float* __restrict__ W3, const float* __restrict__ b3,
    float* __restrict__ out)
{
    const int b = blockIdx.x;
    const int t = threadIdx.x;
    __shared__ float cin[256], a1[128], a2[64];
    cin[t]       = hf[(long)b*128 + t];
    cin[128 + t] = hb[(long)b*128 + t];
    __syncthreads();
    {
        float a = b1[t];
        for (int i = 0; i < 256; ++i) a = fmaf(W1[(long)t*256 + i], cin[i], a);
        a1[t] = a;
    }
    __syncthreads();
    if (t < 64) {
        float a = b2[t];
        for (int i = 0; i < 128; ++i) a = fmaf(W2[(long)t*128 + i], a1[i], a);
        a2[t] = a;
    }
    __syncthreads();
    if (t < 6) {
        float a = b3[t];
        for (int i = 0; i < 64; ++i) a = fmaf(W3[(long)t*64 + i], a2[i], a);
        out[(long)b*6 + t] = a;
    }
}

// ------------------------------------------------------------------- launch
extern "C" void kernel_launch(void* const* d_in, const int* in_sizes, int n_in,
                              void* d_out, int out_size, void* d_ws, size_t ws_size,
                              hipStream_t stream)
{
    const float* x     = (const float*)d_in[0];
    const float* ts    = (const float*)d_in[1];
    const float* w_lin = (const float*)d_in[2];
    const float* b_lin = (const float*)d_in[3];
    const float* w_per = (const float*)d_in[4];
    const float* b_per = (const float*)d_in[5];
    const float* Wq    = (const float*)d_in[6];
    const float* bq    = (const float*)d_in[7];
    const float* Wk    = (const float*)d_in[8];
    const float* bk    = (const float*)d_in[9];
    const float* Wo    = (const float*)d_in[10];
    const float* bo    = (const float*)d_in[11];
    const float* Wih_f = (const float*)d_in[12];
    const float* Whh_f = (const float*)d_in[13];
    const float* bih_f = (const float*)d_in[14];
    const float* bhh_f = (const float*)d_in[15];
    const float* Wih_b = (const float*)d_in[16];
    const float* Whh_b = (const float*)d_in[17];
    const float* bih_b = (const float*)d_in[18];
    const float* bhh_b = (const float*)d_in[19];
    const float* W1    = (const float*)d_in[20];
    const float* b1    = (const float*)d_in[21];
    const float* W2    = (const float*)d_in[22];
    const float* b2    = (const float*)d_in[23];
    const float* W3    = (const float*)d_in[24];
    const float* b3    = (const float*)d_in[25];
    float* out = (float*)d_out;
    float* ws  = (float*)d_ws;

    float* te  = ws + OFF_TE;
    float* q   = ws + OFF_Q;
    float* k   = ws + OFF_K;
    float* ctx = ws + OFF_CTX;
    float* xs  = ws + OFF_XS;
    float* gif = ws + OFF_GIF;
    float* gib = ws + OFF_GIB;
    float* hf  = ws + OFF_HF;
    float* hb  = ws + OFF_HB;

    time_embed_kernel<<<NPOS*128/256, 256, 0, stream>>>(ts, w_lin, b_lin, w_per, b_per, te);
    // q and k projections fused into one launch (z selects param set)
    gemm_dual_kernel<0,0,0><<<dim3(NPOS/64, 1, 2), 256, 0, stream>>>(
        te, Wq, bq, nullptr, q, Wk, bk, nullptr, k, NPOS, 128, 128);
    attn_kernel<<<dim3(16, 4, 30), 256, 0, stream>>>(q, k, x, ctx);
    gemm_mfma_kernel<1,0><<<dim3(NPOS/64, 1), 256, 0, stream>>>(ctx, Wo, bo, nullptr, xs, NPOS, 128, 512);
    // forward and backward gi GEMMs fused into one launch
    gemm_dual_kernel<0,2,1><<<dim3(NPOS/64, 3, 2), 256, 0, stream>>>(
        xs, Wih_f, bih_f, bhh_f, gif, Wih_b, bih_b, bhh_b, gib, NPOS, 384, 128);
    gru_kernel<<<60, 128, 0, stream>>>(gif, gib, Whh_f, bhh_f, Whh_b, bhh_b, hf, hb);
    classifier_kernel<<<30, 128, 0, stream>>>(hf, hb, W1, b1, W2, b2, W3, b3, out);
}